// Round 2
// baseline (668.533 us; speedup 1.0000x reference)
//
#include <hip/hip_runtime.h>

#define HH 512
#define WW 512
#define NPIX (HH * WW)          // 262144
#define NIMG 16
#define KPTS 1024
#define NWORDS (NPIX / 64)      // 4096 u64 mask words per image

// ---------------------------------------------------------------------------
// Kernel 1: binarize + uniform LBP (P=8,R=1) — PURE BOOLEAN form.
// (unchanged from previous round)
// ---------------------------------------------------------------------------
__global__ void lbp_kernel(const float* __restrict__ mo,
                           const float* __restrict__ lb,
                           unsigned long long* __restrict__ maskbits) {
    int m = blockIdx.y;                    // image 0..15: even=pred, odd=mask
    int pix = blockIdx.x * blockDim.x + threadIdx.x;   // 0..262143
    int r = pix >> 9, c = pix & 511;
    int sample = m >> 1;
    const float* img = (m & 1) ? (lb + sample * NPIX) : (mo + sample * NPIX);
    float thr = (m & 1) ? 0.5f : 0.0f;     // sigmoid(x)>0.5 <=> x>0

    int rm = r - (r > 0), rp = r + (r < HH - 1);
    int cm = c - (c > 0), cp = c + (c < WW - 1);
    const float* rowm = img + rm * WW;
    const float* row0 = img + r  * WW;
    const float* rowp = img + rp * WW;

    bool bmm = rowm[cm] > thr, bm0 = rowm[c] > thr, bmp = rowm[cp] > thr;
    bool b0m = row0[cm] > thr, b00 = row0[c] > thr, b0p = row0[cp] > thr;
    bool bpm = rowp[cm] > thr, bp0 = rowp[c] > thr, bpp = rowp[cp] > thr;

    bool r0e = (r == 0), c0e = (c == 0);
    bool t2m = r0e ? bpm : b0m;    // B(row2, cm)
    bool t2c = r0e ? bp0 : b00;    // B(row2, c)
    bool t2p = r0e ? bpp : b0p;    // B(row2, cp)
    bool mc2 = c0e ? bmp : bm0;    // B(rm,  col2)
    bool tc2 = c0e ? t2p : t2c;    // B(row2,col2)
    bool zc2 = c0e ? b0p : b00;    // B(r,   col2)
    bool pc2 = c0e ? bpp : bp0;    // B(rp,  col2)

    unsigned bb =
        (b0p                     ?   1u : 0u)
      | ((bm0 & bmp & t2c & t2p) ?   2u : 0u)
      | (bm0                     ?   4u : 0u)
      | ((bmm & mc2 & t2m & tc2) ?   8u : 0u)
      | (b0m                     ?  16u : 0u)
      | ((b0m & zc2 & bpm & pc2) ?  32u : 0u)
      | (bp0                     ?  64u : 0u)
      | ((b0p & bp0 & bpp)       ? 128u : 0u);

    unsigned rol = ((bb << 1) | (bb >> 7)) & 0xFFu;
    int changes = __popc(bb ^ rol);
    int s = __popc(bb);
    bool maskbit = b00 && (changes <= 2) && (s < 5);   // lbp < THR(=5)

    unsigned long long w = __ballot(maskbit);
    if ((threadIdx.x & 63) == 0)
        maskbits[m * NWORDS + (pix >> 6)] = w;
}

// ---------------------------------------------------------------------------
// Kernel 2: stable row-major compaction to K=1024 packed points per image
// (unchanged)
// ---------------------------------------------------------------------------
__global__ void select_kernel(const unsigned long long* __restrict__ maskbits,
                              unsigned* __restrict__ ptsG) {
    __shared__ unsigned swv[4];
    int m = blockIdx.x, tid = threadIdx.x;
    int lane = tid & 63, wid = tid >> 6;

    for (int i = tid; i < KPTS; i += 256) ptsG[m * KPTS + i] = 0u;
    __syncthreads();

    unsigned running = 0;
    for (int ch = 0; ch < 16; ch++) {
        int w = ch * 256 + tid;
        unsigned long long word = maskbits[m * NWORDS + w];
        unsigned cnt = (unsigned)__popcll(word);

        unsigned x = cnt;                    // intra-wave inclusive scan
#pragma unroll
        for (int d = 1; d < 64; d <<= 1) {
            unsigned y = (unsigned)__shfl_up((int)x, d, 64);
            x += (lane >= d) ? y : 0u;
        }
        if (lane == 63) swv[wid] = x;
        __syncthreads();
        unsigned woff = 0, total = 0;
#pragma unroll
        for (int ww = 0; ww < 4; ww++) {
            unsigned t = swv[ww];
            total += t;
            woff += (ww < wid) ? t : 0u;
        }
        unsigned rank = running + woff + x - cnt;   // exclusive prefix
        while (word) {
            int b = __builtin_ctzll(word);
            word &= word - 1;
            if (rank < (unsigned)KPTS) {
                unsigned p = (unsigned)(w * 64 + b);
                unsigned rr = p >> 9, cc = p & 511u;
                ptsG[m * KPTS + rank] = (rr << 16) | cc;
            }
            rank++;
        }
        running += total;
        if (running >= (unsigned)KPTS) break;   // uniform -> safe
        __syncthreads();   // protect swv before next chunk
    }
}

// ---------------------------------------------------------------------------
// Kernel 3: 4-wave Prim, TWO IMAGES PER BLOCK, software-pipelined.
// Round-1 analysis: exchange round-trip (ds_write->barrier->ds_read ~120cy
// + barrier) is ~100-220 cy of serial dead time per iteration with nothing
// to overlap. Fix: block owns images X and Y; body =
//    [X: read minima -> SEL -> decrease-key -> DPP -> write] -> barrier ->
//    [Y: same] -> (loop, no barrier at seam)
// X's write->read latency elapses under Y's VALU phase and vice versa; the
// single mid-barrier fences BOTH images' write->read pairs (2-buffer parity:
// between any write(p) and its read(p) there is >=1 barrier; between a
// read(p) and the next write(p) there is >=1 barrier). Barriers per
// image-iteration: 0.5 (was 1). Per-image math is bit-identical to round 1
// => identical extraction order; recover/final unchanged.
// ---------------------------------------------------------------------------
typedef short v2s __attribute__((ext_vector_type(2)));
typedef unsigned u32x4 __attribute__((ext_vector_type(4)));

__device__ __forceinline__ int dist2_packed(unsigned a, unsigned b) {
#if __has_builtin(__builtin_amdgcn_sdot2)
    v2s d = __builtin_bit_cast(v2s, a) - __builtin_bit_cast(v2s, b);
    return __builtin_amdgcn_sdot2(d, d, 0, false);
#else
    int dr = (int)(a >> 16) - (int)(b >> 16);
    int dc = (int)(a & 0xFFFFu) - (int)(b & 0xFFFFu);
    return __mul24(dr, dr) + __mul24(dc, dc);
#endif
}

template <int CTRL>
__device__ __forceinline__ unsigned umin_dpp(unsigned x) {
    unsigned o = (unsigned)__builtin_amdgcn_update_dpp((int)x, (int)x, CTRL,
                                                       0xf, 0xf, false);
    return o < x ? o : x;
}

// full-wave unsigned-min; result valid in lane 63 only.
__device__ __forceinline__ unsigned wave_min_to_lane63(unsigned x) {
    x = umin_dpp<0x111>(x);   // row_shr:1
    x = umin_dpp<0x112>(x);   // row_shr:2
    x = umin_dpp<0x114>(x);   // row_shr:4
    x = umin_dpp<0x118>(x);   // row_shr:8  -> lane15 of each 16-row
    x = umin_dpp<0x142>(x);   // row_bcast:15
    x = umin_dpp<0x143>(x);   // row_bcast:31 -> lane63 = wave min
    return x;
}

__device__ __forceinline__ unsigned umin3(unsigned a, unsigned b, unsigned c) {
    unsigned t = a < b ? a : b;          // fuses to v_min3_u32
    return t < c ? t : c;
}

// biased key: coords pre-shifted <<5 so sdot2 gives d2<<10; acc = idx-1024
__device__ __forceinline__ unsigned mk_key(unsigned ps, unsigned qs, int izb) {
#if __has_builtin(__builtin_amdgcn_sdot2)
    v2s d = __builtin_bit_cast(v2s, ps) - __builtin_bit_cast(v2s, qs);
    return (unsigned)__builtin_amdgcn_sdot2(d, d, izb, false);
#else
    int dr = (int)(short)(ps >> 16) - (int)(short)(qs >> 16);
    int dc = (int)(short)(ps & 0xFFFFu) - (int)(short)(qs & 0xFFFFu);
    return (unsigned)(dr * dr + dc * dc + izb);
#endif
}

// uniform select of points[wslot][wlane] from 16 replicated regs, prefix P
#define SEL16(P, res)                                                     \
    { unsigned _a0 = b0 ? P##1  : P##0;                                   \
      unsigned _a1 = b0 ? P##3  : P##2;                                   \
      unsigned _a2 = b0 ? P##5  : P##4;                                   \
      unsigned _a3 = b0 ? P##7  : P##6;                                   \
      unsigned _a4 = b0 ? P##9  : P##8;                                   \
      unsigned _a5 = b0 ? P##11 : P##10;                                  \
      unsigned _a6 = b0 ? P##13 : P##12;                                  \
      unsigned _a7 = b0 ? P##15 : P##14;                                  \
      unsigned _c0 = b1 ? _a1 : _a0;                                      \
      unsigned _c1 = b1 ? _a3 : _a2;                                      \
      unsigned _c2 = b1 ? _a5 : _a4;                                      \
      unsigned _c3 = b1 ? _a7 : _a6;                                      \
      unsigned _e0 = b2 ? _c1 : _c0;                                      \
      unsigned _e1 = b2 ? _c3 : _c2;                                      \
      res = b3 ? _e1 : _e0; }

// load 16 replicated point regs for image with base pointer B, prefix P
#define LOADP(P, B)                                                       \
    unsigned P##0  = B[( 0 << 6) | lane] << 5;                            \
    unsigned P##1  = B[( 1 << 6) | lane] << 5;                            \
    unsigned P##2  = B[( 2 << 6) | lane] << 5;                            \
    unsigned P##3  = B[( 3 << 6) | lane] << 5;                            \
    unsigned P##4  = B[( 4 << 6) | lane] << 5;                            \
    unsigned P##5  = B[( 5 << 6) | lane] << 5;                            \
    unsigned P##6  = B[( 6 << 6) | lane] << 5;                            \
    unsigned P##7  = B[( 7 << 6) | lane] << 5;                            \
    unsigned P##8  = B[( 8 << 6) | lane] << 5;                            \
    unsigned P##9  = B[( 9 << 6) | lane] << 5;                            \
    unsigned P##10 = B[(10 << 6) | lane] << 5;                            \
    unsigned P##11 = B[(11 << 6) | lane] << 5;                            \
    unsigned P##12 = B[(12 << 6) | lane] << 5;                            \
    unsigned P##13 = B[(13 << 6) | lane] << 5;                            \
    unsigned P##14 = B[(14 << 6) | lane] << 5;                            \
    unsigned P##15 = B[(15 << 6) | lane] << 5;

// one image's pipeline phase: read minima(par) -> wk -> pjs -> record ->
// decrease-key -> per-lane min -> DPP -> write minima(par^1)
#define MST_PHASE(P, OQ, OK, ACC, XI) do {                                \
    u32x4 _xv = *reinterpret_cast<const u32x4*>(&xm[XI][par][0]);         \
    unsigned _vm = umin3(_xv.x, _xv.y, _xv.z);                            \
    _vm = _vm < _xv.w ? _vm : _xv.w;                                      \
    unsigned _wk = (unsigned)__builtin_amdgcn_readfirstlane((int)_vm) + 1024u; \
    unsigned _j = _wk & 1023u;                                            \
    int _ws = (int)(_j >> 6), _wl = (int)(_j & 63u);                      \
    bool b0 = (_ws & 1) != 0, b1 = (_ws & 2) != 0;                        \
    bool b2 = (_ws & 4) != 0, b3 = (_ws & 8) != 0;                        \
    unsigned _sel; SEL16(P, _sel);                                        \
    unsigned _pjs = (unsigned)__builtin_amdgcn_readlane((int)_sel, _wl);  \
    ACC = (lane == t) ? _wk : ACC;                                        \
    { unsigned _nk = mk_key(OQ##0, _pjs, oi0);                            \
      OK##0 = (unsigned)min((int)OK##0, (int)_nk); }                      \
    { unsigned _nk = mk_key(OQ##1, _pjs, oi1);                            \
      OK##1 = (unsigned)min((int)OK##1, (int)_nk); }                      \
    { unsigned _nk = mk_key(OQ##2, _pjs, oi2);                            \
      OK##2 = (unsigned)min((int)OK##2, (int)_nk); }                      \
    { unsigned _nk = mk_key(OQ##3, _pjs, oi3);                            \
      OK##3 = (unsigned)min((int)OK##3, (int)_nk); }                      \
    unsigned _r3 = umin3(OK##0, OK##1, OK##2);                            \
    unsigned _rk = _r3 < OK##3 ? _r3 : OK##3;                             \
    unsigned _wm = wave_min_to_lane63(_rk);                               \
    if (lane == 63) xm[XI][par ^ 1][wid] = _wm;                           \
} while (0)

__global__ __launch_bounds__(256, 1) void mst_kernel(const unsigned* __restrict__ ptsG,
                                                     unsigned* __restrict__ edgesG) {
    __shared__ __align__(16) unsigned xm[2][2][4];   // [img][par][wave]
    int tid = threadIdx.x;
    int lane = tid & 63, wid = tid >> 6;
    int b = blockIdx.x;                              // 0..7
    const unsigned* baseX = ptsG + (2 * b)     * KPTS;
    const unsigned* baseY = ptsG + (2 * b + 1) * KPTS;
    unsigned pt0sX = baseX[0] << 5;                  // uniform self point 0
    unsigned pt0sY = baseY[0] << 5;

    // replicated point sets (feed SEL16 in every wave)
    LOADP(pX, baseX)
    LOADP(pY, baseY)

    // own key slots: global slot = wid*4 + sl ; oi shared (image-independent)
    int oi0 = (((wid * 4 + 0) << 6) | lane) - 1024;
    int oi1 = (((wid * 4 + 1) << 6) | lane) - 1024;
    int oi2 = (((wid * 4 + 2) << 6) | lane) - 1024;
    int oi3 = (((wid * 4 + 3) << 6) | lane) - 1024;

    unsigned oqX0 = pX0, oqX1, oqX2, oqX3;   // wave wid owns slots wid*4..+3
    unsigned oqY0, oqY1, oqY2, oqY3;
    // own q regs: select from replicated set (slot index = wid*4+sl, but the
    // replicated regs are indexed by slot constant — just reload from memory,
    // simplest and off the critical loop)
    oqX0 = baseX[((wid * 4 + 0) << 6) | lane] << 5;
    oqX1 = baseX[((wid * 4 + 1) << 6) | lane] << 5;
    oqX2 = baseX[((wid * 4 + 2) << 6) | lane] << 5;
    oqX3 = baseX[((wid * 4 + 3) << 6) | lane] << 5;
    oqY0 = baseY[((wid * 4 + 0) << 6) | lane] << 5;
    oqY1 = baseY[((wid * 4 + 1) << 6) | lane] << 5;
    oqY2 = baseY[((wid * 4 + 2) << 6) | lane] << 5;
    oqY3 = baseY[((wid * 4 + 3) << 6) | lane] << 5;

    unsigned okX0 = mk_key(oqX0, pt0sX, oi0);   // node0 self-kills
    unsigned okX1 = mk_key(oqX1, pt0sX, oi1);
    unsigned okX2 = mk_key(oqX2, pt0sX, oi2);
    unsigned okX3 = mk_key(oqX3, pt0sX, oi3);
    unsigned okY0 = mk_key(oqY0, pt0sY, oi0);
    unsigned okY1 = mk_key(oqY1, pt0sY, oi1);
    unsigned okY2 = mk_key(oqY2, pt0sY, oi2);
    unsigned okY3 = mk_key(oqY3, pt0sY, oi3);

    unsigned* eoutX = edgesG + (2 * b)     * KPTS;
    unsigned* eoutY = edgesG + (2 * b + 1) * KPTS;

    // prologue: initial per-lane mins -> DPP -> write buf 0 for both images
    {
        unsigned r3 = umin3(okX0, okX1, okX2);
        unsigned rk = r3 < okX3 ? r3 : okX3;
        unsigned wm = wave_min_to_lane63(rk);
        if (lane == 63) xm[0][0][wid] = wm;
    }
    {
        unsigned r3 = umin3(okY0, okY1, okY2);
        unsigned rk = r3 < okY3 ? r3 : okY3;
        unsigned wm = wave_min_to_lane63(rk);
        if (lane == 63) xm[1][0][wid] = wm;
    }
    __syncthreads();

    unsigned accX = 0, accY = 0;
    int par = 0;

    for (int chk = 0; chk < 16; chk++) {
        int tmax = (chk < 15) ? 64 : 63;     // 15*64 + 63 = 1023 iterations
        for (int t = 0; t < tmax; t++) {
            MST_PHASE(pX, oqX, okX, accX, 0);
            __syncthreads();                 // fences X-write & Y-write pairs
            MST_PHASE(pY, oqY, okY, accY, 1);
            par ^= 1;                        // no barrier at Y->X seam
        }
        // coalesced batch stores; chk=15 lane63 writes stale eout[1023]
        // (never read by recover_kernel). acc is uniform across waves.
        if (wid == 0) eoutX[(chk << 6) + lane] = accX;
        if (wid == 1) eoutY[(chk << 6) + lane] = accY;
    }
}

// ---------------------------------------------------------------------------
// Kernel 4 (phase 2): recover src per edge + per-edge (Dp-Dm)^2.
// (unchanged)
// ---------------------------------------------------------------------------
__global__ void recover_kernel(const unsigned* __restrict__ ptsG,
                               const unsigned* __restrict__ edgesG,
                               float* __restrict__ contrib) {
    __shared__ unsigned sS[KPTS];
    __shared__ unsigned sO[KPTS];
    __shared__ unsigned short sT[KPTS];   // extraction time + 1 (0 = root)
    int g = blockIdx.x, m = blockIdx.y;
    int tid = threadIdx.x;
    int partner = m ^ 1;

    for (int i = tid; i < KPTS; i += 256) {
        sS[i] = ptsG[m * KPTS + i];
        sO[i] = ptsG[partner * KPTS + i];
    }
    for (int e = tid; e < KPTS - 1; e += 256) {
        unsigned wkk = edgesG[m * KPTS + e];
        sT[wkk & 1023u] = (unsigned short)(e + 1);
    }
    if (tid == 0) sT[0] = 0;
    __syncthreads();

    int lane = tid & 63, w = tid >> 6;
    for (int k = 0; k < 16; k++) {
        int e = g * 64 + w * 16 + k;
        if (e >= KPTS - 1) break;            // only e=1023 (g=15,w=3,k=15)
        unsigned wk = edgesG[m * KPTS + e];
        unsigned j = wk & 1023u;
        unsigned d2p = wk >> 10;
        unsigned pj = sS[j];
        unsigned te1 = (unsigned)(e + 1);

        unsigned best = 0xFFFFFFFFu;
#pragma unroll
        for (int i = 0; i < 16; i++) {
            int v = i * 64 + lane;
            unsigned pv = sS[v];
            int d2 = dist2_packed(pv, pj);
            unsigned tv1 = (unsigned)sT[v];
            bool qual = ((unsigned)d2 == d2p) && (tv1 < te1);
            unsigned cand = qual ? ((tv1 << 10) | (unsigned)v) : 0xFFFFFFFFu;
            best = cand < best ? cand : best;
        }
#pragma unroll
        for (int dd = 32; dd; dd >>= 1) {
            unsigned o = (unsigned)__shfl_xor((int)best, dd, 64);
            best = o < best ? o : best;
        }
        unsigned vsrc = best & 1023u;
        if (lane == 0) {
            unsigned oj = sO[j], os = sO[vsrc];
            float Dp = __fsqrt_rn((float)d2p);
            float Dm = __fsqrt_rn((float)dist2_packed(oj, os));
            float diff = Dp - Dm;
            contrib[m * (KPTS - 1) + e] = diff * diff;
        }
    }
}

// ---------------------------------------------------------------------------
// Kernel 5: per-image f64 sum (extraction order, deterministic) -> loss
// (unchanged)
// ---------------------------------------------------------------------------
__global__ void final_kernel(const float* __restrict__ contrib,
                             float* __restrict__ out) {
    __shared__ double part[NIMG];
    int t = threadIdx.x;
    if (t < NIMG) {
        double s = 0.0;
        for (int e = 0; e < KPTS - 1; e++)
            s += (double)contrib[t * (KPTS - 1) + e];
        part[t] = sqrt(s);
    }
    __syncthreads();
    if (t == 0) {
        double tot = 0.0;
        for (int i = 0; i < NIMG; i++) tot += part[i];
        out[0] = (float)(0.1 * tot / 8.0);
    }
}

// ---------------------------------------------------------------------------
// ws layout:
//   [0,512K)     maskbits (lbp->select), then DEAD:
//   [0,64K)      edgesG   (mst->recover)   — overlaps dead maskbits
//   [64K,128K)   contrib  (recover->final) — overlaps dead maskbits
//   [512K,576K)  ptsG     (select->mst/recover)
// ---------------------------------------------------------------------------
extern "C" void kernel_launch(void* const* d_in, const int* in_sizes, int n_in,
                              void* d_out, int out_size, void* d_ws, size_t ws_size,
                              hipStream_t stream) {
    const float* mo = (const float*)d_in[1];   // model_output
    const float* lb = (const float*)d_in[2];   // labels

    unsigned long long* maskbits = (unsigned long long*)d_ws;
    unsigned* edgesG = (unsigned*)d_ws;
    float* contrib = (float*)((char*)d_ws + (size_t)64 * 1024);
    unsigned* ptsG = (unsigned*)((char*)d_ws + (size_t)NIMG * NWORDS * 8);
    float* out = (float*)d_out;

    lbp_kernel<<<dim3(NPIX / 256, NIMG), 256, 0, stream>>>(mo, lb, maskbits);
    select_kernel<<<NIMG, 256, 0, stream>>>(maskbits, ptsG);
    mst_kernel<<<NIMG / 2, 256, 0, stream>>>(ptsG, edgesG);
    recover_kernel<<<dim3(16, NIMG), 256, 0, stream>>>(ptsG, edgesG, contrib);
    final_kernel<<<1, 64, 0, stream>>>(contrib, out);
}

// Round 3
// 541.824 us; speedup vs baseline: 1.2339x; 1.2339x over previous
//
#include <hip/hip_runtime.h>

#define HH 512
#define WW 512
#define NPIX (HH * WW)          // 262144
#define NIMG 16
#define KPTS 1024
#define NWORDS (NPIX / 64)      // 4096 u64 mask words per image

// ---------------------------------------------------------------------------
// Kernel 1: binarize + uniform LBP (P=8,R=1) — PURE BOOLEAN form. (unchanged)
// ---------------------------------------------------------------------------
__global__ void lbp_kernel(const float* __restrict__ mo,
                           const float* __restrict__ lb,
                           unsigned long long* __restrict__ maskbits) {
    int m = blockIdx.y;                    // image 0..15: even=pred, odd=mask
    int pix = blockIdx.x * blockDim.x + threadIdx.x;   // 0..262143
    int r = pix >> 9, c = pix & 511;
    int sample = m >> 1;
    const float* img = (m & 1) ? (lb + sample * NPIX) : (mo + sample * NPIX);
    float thr = (m & 1) ? 0.5f : 0.0f;     // sigmoid(x)>0.5 <=> x>0

    int rm = r - (r > 0), rp = r + (r < HH - 1);
    int cm = c - (c > 0), cp = c + (c < WW - 1);
    const float* rowm = img + rm * WW;
    const float* row0 = img + r  * WW;
    const float* rowp = img + rp * WW;

    bool bmm = rowm[cm] > thr, bm0 = rowm[c] > thr, bmp = rowm[cp] > thr;
    bool b0m = row0[cm] > thr, b00 = row0[c] > thr, b0p = row0[cp] > thr;
    bool bpm = rowp[cm] > thr, bp0 = rowp[c] > thr, bpp = rowp[cp] > thr;

    bool r0e = (r == 0), c0e = (c == 0);
    bool t2m = r0e ? bpm : b0m;    // B(row2, cm)
    bool t2c = r0e ? bp0 : b00;    // B(row2, c)
    bool t2p = r0e ? bpp : b0p;    // B(row2, cp)
    bool mc2 = c0e ? bmp : bm0;    // B(rm,  col2)
    bool tc2 = c0e ? t2p : t2c;    // B(row2,col2)
    bool zc2 = c0e ? b0p : b00;    // B(r,   col2)
    bool pc2 = c0e ? bpp : bp0;    // B(rp,  col2)

    unsigned bb =
        (b0p                     ?   1u : 0u)
      | ((bm0 & bmp & t2c & t2p) ?   2u : 0u)
      | (bm0                     ?   4u : 0u)
      | ((bmm & mc2 & t2m & tc2) ?   8u : 0u)
      | (b0m                     ?  16u : 0u)
      | ((b0m & zc2 & bpm & pc2) ?  32u : 0u)
      | (bp0                     ?  64u : 0u)
      | ((b0p & bp0 & bpp)       ? 128u : 0u);

    unsigned rol = ((bb << 1) | (bb >> 7)) & 0xFFu;
    int changes = __popc(bb ^ rol);
    int s = __popc(bb);
    bool maskbit = b00 && (changes <= 2) && (s < 5);   // lbp < THR(=5)

    unsigned long long w = __ballot(maskbit);
    if ((threadIdx.x & 63) == 0)
        maskbits[m * NWORDS + (pix >> 6)] = w;
}

// ---------------------------------------------------------------------------
// Kernel 2: stable row-major compaction to K=1024 packed points per image
// (unchanged)
// ---------------------------------------------------------------------------
__global__ void select_kernel(const unsigned long long* __restrict__ maskbits,
                              unsigned* __restrict__ ptsG) {
    __shared__ unsigned swv[4];
    int m = blockIdx.x, tid = threadIdx.x;
    int lane = tid & 63, wid = tid >> 6;

    for (int i = tid; i < KPTS; i += 256) ptsG[m * KPTS + i] = 0u;
    __syncthreads();

    unsigned running = 0;
    for (int ch = 0; ch < 16; ch++) {
        int w = ch * 256 + tid;
        unsigned long long word = maskbits[m * NWORDS + w];
        unsigned cnt = (unsigned)__popcll(word);

        unsigned x = cnt;                    // intra-wave inclusive scan
#pragma unroll
        for (int d = 1; d < 64; d <<= 1) {
            unsigned y = (unsigned)__shfl_up((int)x, d, 64);
            x += (lane >= d) ? y : 0u;
        }
        if (lane == 63) swv[wid] = x;
        __syncthreads();
        unsigned woff = 0, total = 0;
#pragma unroll
        for (int ww = 0; ww < 4; ww++) {
            unsigned t = swv[ww];
            total += t;
            woff += (ww < wid) ? t : 0u;
        }
        unsigned rank = running + woff + x - cnt;   // exclusive prefix
        while (word) {
            int b = __builtin_ctzll(word);
            word &= word - 1;
            if (rank < (unsigned)KPTS) {
                unsigned p = (unsigned)(w * 64 + b);
                unsigned rr = p >> 9, cc = p & 511u;
                ptsG[m * KPTS + rank] = (rr << 16) | cc;
            }
            rank++;
        }
        running += total;
        if (running >= (unsigned)KPTS) break;   // uniform -> safe
        __syncthreads();   // protect swv before next chunk
    }
}

// ---------------------------------------------------------------------------
// Kernel 3: 4-wave Prim, ONE image per block (round-2's X/Y pairing reverted:
// in-order waves serialize the two chains; wall = 1023 * chain latency).
// Exchange de-fattened two ways vs round-1:
//  (1) BARRIER-FREE TAGGED PING-PONG. Live keys < 2^29 (max d2=522242 ->
//      key < 0x1FE00400), so bits 29..31 are free: lane63 writes
//      min(wmin,0x1FFFFFFF) | ((it+1)&7)<<29 ; readers spin on volatile
//      ds_read until all 4 tags match it&7. Safety induction: wave w can
//      write iter i only after reading all slots of i-1, which required
//      every wave to write i-1, which required every wave to READ i-2 —
//      so the i-2 value being overwritten is provably consumed. b32 writes
//      can't tear; one __syncthreads after the prologue kills the
//      garbage-LDS-matches-tag-0 case. Dead-wave minima (>=2^31) clamp to
//      0x1FFFFFFF which still loses to every live key.
//  (2) readfirstlane moved OFF the SEL16 path: b0..b3 come from VGPR
//      compares on vm (bits 6..9 of vm == bits of j since +1024 only sets
//      bit10); readfirstlane(vm)&63 (the readlane index) runs in parallel
//      with the SEL16 tree; acc record uses VGPR wk.
// Key math bit-identical to round 1 => identical extraction order.
// ---------------------------------------------------------------------------
typedef short v2s __attribute__((ext_vector_type(2)));

__device__ __forceinline__ int dist2_packed(unsigned a, unsigned b) {
#if __has_builtin(__builtin_amdgcn_sdot2)
    v2s d = __builtin_bit_cast(v2s, a) - __builtin_bit_cast(v2s, b);
    return __builtin_amdgcn_sdot2(d, d, 0, false);
#else
    int dr = (int)(a >> 16) - (int)(b >> 16);
    int dc = (int)(a & 0xFFFFu) - (int)(b & 0xFFFFu);
    return __mul24(dr, dr) + __mul24(dc, dc);
#endif
}

template <int CTRL>
__device__ __forceinline__ unsigned umin_dpp(unsigned x) {
    unsigned o = (unsigned)__builtin_amdgcn_update_dpp((int)x, (int)x, CTRL,
                                                       0xf, 0xf, false);
    return o < x ? o : x;
}

// full-wave unsigned-min; result valid in lane 63 only.
__device__ __forceinline__ unsigned wave_min_to_lane63(unsigned x) {
    x = umin_dpp<0x111>(x);   // row_shr:1
    x = umin_dpp<0x112>(x);   // row_shr:2
    x = umin_dpp<0x114>(x);   // row_shr:4
    x = umin_dpp<0x118>(x);   // row_shr:8  -> lane15 of each 16-row
    x = umin_dpp<0x142>(x);   // row_bcast:15
    x = umin_dpp<0x143>(x);   // row_bcast:31 -> lane63 = wave min
    return x;
}

__device__ __forceinline__ unsigned umin3(unsigned a, unsigned b, unsigned c) {
    unsigned t = a < b ? a : b;          // fuses to v_min3_u32
    return t < c ? t : c;
}

// biased key: coords pre-shifted <<5 so sdot2 gives d2<<10; acc = idx-1024
__device__ __forceinline__ unsigned mk_key(unsigned ps, unsigned qs, int izb) {
#if __has_builtin(__builtin_amdgcn_sdot2)
    v2s d = __builtin_bit_cast(v2s, ps) - __builtin_bit_cast(v2s, qs);
    return (unsigned)__builtin_amdgcn_sdot2(d, d, izb, false);
#else
    int dr = (int)(short)(ps >> 16) - (int)(short)(qs >> 16);
    int dc = (int)(short)(ps & 0xFFFFu) - (int)(short)(qs & 0xFFFFu);
    return (unsigned)(dr * dr + dc * dc + izb);
#endif
}

// uniform select of points[wslot][.] from 16 replicated regs, prefix P;
// bools b0..b3 in scope (VGPR-derived, uniform content)
#define SEL16(P, res)                                                     \
    { unsigned _a0 = b0 ? P##1  : P##0;                                   \
      unsigned _a1 = b0 ? P##3  : P##2;                                   \
      unsigned _a2 = b0 ? P##5  : P##4;                                   \
      unsigned _a3 = b0 ? P##7  : P##6;                                   \
      unsigned _a4 = b0 ? P##9  : P##8;                                   \
      unsigned _a5 = b0 ? P##11 : P##10;                                  \
      unsigned _a6 = b0 ? P##13 : P##12;                                  \
      unsigned _a7 = b0 ? P##15 : P##14;                                  \
      unsigned _c0 = b1 ? _a1 : _a0;                                      \
      unsigned _c1 = b1 ? _a3 : _a2;                                      \
      unsigned _c2 = b1 ? _a5 : _a4;                                      \
      unsigned _c3 = b1 ? _a7 : _a6;                                      \
      unsigned _e0 = b2 ? _c1 : _c0;                                      \
      unsigned _e1 = b2 ? _c3 : _c2;                                      \
      res = b3 ? _e1 : _e0; }

#define LOADP(P, B)                                                       \
    unsigned P##0  = B[( 0 << 6) | lane] << 5;                            \
    unsigned P##1  = B[( 1 << 6) | lane] << 5;                            \
    unsigned P##2  = B[( 2 << 6) | lane] << 5;                            \
    unsigned P##3  = B[( 3 << 6) | lane] << 5;                            \
    unsigned P##4  = B[( 4 << 6) | lane] << 5;                            \
    unsigned P##5  = B[( 5 << 6) | lane] << 5;                            \
    unsigned P##6  = B[( 6 << 6) | lane] << 5;                            \
    unsigned P##7  = B[( 7 << 6) | lane] << 5;                            \
    unsigned P##8  = B[( 8 << 6) | lane] << 5;                            \
    unsigned P##9  = B[( 9 << 6) | lane] << 5;                            \
    unsigned P##10 = B[(10 << 6) | lane] << 5;                            \
    unsigned P##11 = B[(11 << 6) | lane] << 5;                            \
    unsigned P##12 = B[(12 << 6) | lane] << 5;                            \
    unsigned P##13 = B[(13 << 6) | lane] << 5;                            \
    unsigned P##14 = B[(14 << 6) | lane] << 5;                            \
    unsigned P##15 = B[(15 << 6) | lane] << 5;

#define KMAX29 0x1FFFFFFFu

__global__ __launch_bounds__(256, 1) void mst_kernel(const unsigned* __restrict__ ptsG,
                                                     unsigned* __restrict__ edgesG) {
    __shared__ __align__(16) unsigned xm[2][4];   // [parity][wave] tagged mins
    int tid = threadIdx.x;
    int lane = tid & 63, wid = tid >> 6;
    int m = blockIdx.x;
    const unsigned* base = ptsG + m * KPTS;
    unsigned pt0s = base[0] << 5;                 // uniform self point 0

    LOADP(p, base)                                // replicated point set

    // own key slots: global slot = wid*4 + sl
    int oi0 = (((wid * 4 + 0) << 6) | lane) - 1024;
    int oi1 = (((wid * 4 + 1) << 6) | lane) - 1024;
    int oi2 = (((wid * 4 + 2) << 6) | lane) - 1024;
    int oi3 = (((wid * 4 + 3) << 6) | lane) - 1024;
    unsigned oq0 = base[((wid * 4 + 0) << 6) | lane] << 5;
    unsigned oq1 = base[((wid * 4 + 1) << 6) | lane] << 5;
    unsigned oq2 = base[((wid * 4 + 2) << 6) | lane] << 5;
    unsigned oq3 = base[((wid * 4 + 3) << 6) | lane] << 5;
    unsigned ok0 = mk_key(oq0, pt0s, oi0);        // node0 self-kills
    unsigned ok1 = mk_key(oq1, pt0s, oi1);
    unsigned ok2 = mk_key(oq2, pt0s, oi2);
    unsigned ok3 = mk_key(oq3, pt0s, oi3);

    unsigned* eout = edgesG + m * KPTS;

    // prologue: initial wave-min -> tagged write, buf 0, tag 0
    {
        unsigned r3 = umin3(ok0, ok1, ok2);
        unsigned rk = r3 < ok3 ? r3 : ok3;
        unsigned wm = wave_min_to_lane63(rk);
        if (lane == 63) {
            unsigned tv = (wm < KMAX29 ? wm : KMAX29);   // tag 0
            *(volatile unsigned*)&xm[0][wid] = tv;
        }
    }
    __syncthreads();          // the ONLY barrier: fences garbage-LDS at t=0

    unsigned acc = 0;

    for (int chk = 0; chk < 16; chk++) {
        int tmax = (chk < 15) ? 64 : 63;     // 15*64 + 63 = 1023 iterations
        for (int t = 0; t < tmax; t++) {
            int it = (chk << 6) + t;         // global iteration 0..1022

            // ---- tagged spin-read of the 4 wave minima ----
            const volatile unsigned* src = &xm[it & 1][0];
            unsigned etag = (unsigned)(it & 7) << 29;
            unsigned d0, d1, d2, d3;
            for (;;) {
                unsigned x0 = src[0], x1 = src[1], x2 = src[2], x3 = src[3];
                d0 = x0 ^ etag; d1 = x1 ^ etag; d2 = x2 ^ etag; d3 = x3 ^ etag;
                if ((((d0 | d1) | (d2 | d3)) >> 29) == 0u) break;  // tags ok
            }
            // d0..d3 are tag-stripped minima when tags matched
            unsigned vm = umin3(d0, d1, d2);
            vm = vm < d3 ? vm : d3;          // uniform-content VGPR

            // scalar path (parallel with SEL16): readlane index only
            int wl = __builtin_amdgcn_readfirstlane((int)vm) & 63;

            // vector path: wk + slot bools straight from vm (bit10-add
            // doesn't touch bits 0..9)
            unsigned wkv = vm + 1024u;
            bool b0 = (vm & 64u)  != 0u;
            bool b1 = (vm & 128u) != 0u;
            bool b2 = (vm & 256u) != 0u;
            bool b3 = (vm & 512u) != 0u;
            unsigned sel;
            SEL16(p, sel);
            unsigned pjs = (unsigned)__builtin_amdgcn_readlane((int)sel, wl);

            // ---- edge record: cndmask accumulate into lane t ----
            acc = (lane == t) ? wkv : acc;

            // ---- decrease-key; extracted slot self-kills (d2=0 -> neg) ----
            { unsigned nk = mk_key(oq0, pjs, oi0);
              ok0 = (unsigned)min((int)ok0, (int)nk); }
            { unsigned nk = mk_key(oq1, pjs, oi1);
              ok1 = (unsigned)min((int)ok1, (int)nk); }
            { unsigned nk = mk_key(oq2, pjs, oi2);
              ok2 = (unsigned)min((int)ok2, (int)nk); }
            { unsigned nk = mk_key(oq3, pjs, oi3);
              ok3 = (unsigned)min((int)ok3, (int)nk); }
            unsigned r3 = umin3(ok0, ok1, ok2);
            unsigned rk = r3 < ok3 ? r3 : ok3;

            // ---- per-wave reduce + tagged write (no barrier) ----
            unsigned wm = wave_min_to_lane63(rk);
            if (lane == 63) {
                unsigned tv = (wm < KMAX29 ? wm : KMAX29)
                            | ((unsigned)((it + 1) & 7) << 29);
                *(volatile unsigned*)&xm[(it + 1) & 1][wid] = tv;
            }
        }
        // acc is identical in all waves; distribute chunk stores round-robin
        if (wid == (chk & 3)) eout[(chk << 6) + lane] = acc;
    }
}

// ---------------------------------------------------------------------------
// Kernel 4 (phase 2): recover src per edge + per-edge (Dp-Dm)^2. (unchanged)
// ---------------------------------------------------------------------------
__global__ void recover_kernel(const unsigned* __restrict__ ptsG,
                               const unsigned* __restrict__ edgesG,
                               float* __restrict__ contrib) {
    __shared__ unsigned sS[KPTS];
    __shared__ unsigned sO[KPTS];
    __shared__ unsigned short sT[KPTS];   // extraction time + 1 (0 = root)
    int g = blockIdx.x, m = blockIdx.y;
    int tid = threadIdx.x;
    int partner = m ^ 1;

    for (int i = tid; i < KPTS; i += 256) {
        sS[i] = ptsG[m * KPTS + i];
        sO[i] = ptsG[partner * KPTS + i];
    }
    for (int e = tid; e < KPTS - 1; e += 256) {
        unsigned wkk = edgesG[m * KPTS + e];
        sT[wkk & 1023u] = (unsigned short)(e + 1);
    }
    if (tid == 0) sT[0] = 0;
    __syncthreads();

    int lane = tid & 63, w = tid >> 6;
    for (int k = 0; k < 16; k++) {
        int e = g * 64 + w * 16 + k;
        if (e >= KPTS - 1) break;            // only e=1023 (g=15,w=3,k=15)
        unsigned wk = edgesG[m * KPTS + e];
        unsigned j = wk & 1023u;
        unsigned d2p = wk >> 10;
        unsigned pj = sS[j];
        unsigned te1 = (unsigned)(e + 1);

        unsigned best = 0xFFFFFFFFu;
#pragma unroll
        for (int i = 0; i < 16; i++) {
            int v = i * 64 + lane;
            unsigned pv = sS[v];
            int d2 = dist2_packed(pv, pj);
            unsigned tv1 = (unsigned)sT[v];
            bool qual = ((unsigned)d2 == d2p) && (tv1 < te1);
            unsigned cand = qual ? ((tv1 << 10) | (unsigned)v) : 0xFFFFFFFFu;
            best = cand < best ? cand : best;
        }
#pragma unroll
        for (int dd = 32; dd; dd >>= 1) {
            unsigned o = (unsigned)__shfl_xor((int)best, dd, 64);
            best = o < best ? o : best;
        }
        unsigned vsrc = best & 1023u;
        if (lane == 0) {
            unsigned oj = sO[j], os = sO[vsrc];
            float Dp = __fsqrt_rn((float)d2p);
            float Dm = __fsqrt_rn((float)dist2_packed(oj, os));
            float diff = Dp - Dm;
            contrib[m * (KPTS - 1) + e] = diff * diff;
        }
    }
}

// ---------------------------------------------------------------------------
// Kernel 5: per-image f64 sum (extraction order, deterministic) -> loss
// (unchanged)
// ---------------------------------------------------------------------------
__global__ void final_kernel(const float* __restrict__ contrib,
                             float* __restrict__ out) {
    __shared__ double part[NIMG];
    int t = threadIdx.x;
    if (t < NIMG) {
        double s = 0.0;
        for (int e = 0; e < KPTS - 1; e++)
            s += (double)contrib[t * (KPTS - 1) + e];
        part[t] = sqrt(s);
    }
    __syncthreads();
    if (t == 0) {
        double tot = 0.0;
        for (int i = 0; i < NIMG; i++) tot += part[i];
        out[0] = (float)(0.1 * tot / 8.0);
    }
}

// ---------------------------------------------------------------------------
// ws layout:
//   [0,512K)     maskbits (lbp->select), then DEAD:
//   [0,64K)      edgesG   (mst->recover)   — overlaps dead maskbits
//   [64K,128K)   contrib  (recover->final) — overlaps dead maskbits
//   [512K,576K)  ptsG     (select->mst/recover)
// ---------------------------------------------------------------------------
extern "C" void kernel_launch(void* const* d_in, const int* in_sizes, int n_in,
                              void* d_out, int out_size, void* d_ws, size_t ws_size,
                              hipStream_t stream) {
    const float* mo = (const float*)d_in[1];   // model_output
    const float* lb = (const float*)d_in[2];   // labels

    unsigned long long* maskbits = (unsigned long long*)d_ws;
    unsigned* edgesG = (unsigned*)d_ws;
    float* contrib = (float*)((char*)d_ws + (size_t)64 * 1024);
    unsigned* ptsG = (unsigned*)((char*)d_ws + (size_t)NIMG * NWORDS * 8);
    float* out = (float*)d_out;

    lbp_kernel<<<dim3(NPIX / 256, NIMG), 256, 0, stream>>>(mo, lb, maskbits);
    select_kernel<<<NIMG, 256, 0, stream>>>(maskbits, ptsG);
    mst_kernel<<<NIMG, 256, 0, stream>>>(ptsG, edgesG);
    recover_kernel<<<dim3(16, NIMG), 256, 0, stream>>>(ptsG, edgesG, contrib);
    final_kernel<<<1, 64, 0, stream>>>(contrib, out);
}

// Round 5
// 527.920 us; speedup vs baseline: 1.2664x; 1.0263x over previous
//
#include <hip/hip_runtime.h>

#define HH 512
#define WW 512
#define NPIX (HH * WW)          // 262144
#define NIMG 16
#define KPTS 1024
#define NWORDS (NPIX / 64)      // 4096 u64 mask words per image

// ---------------------------------------------------------------------------
// Kernel 1: binarize + uniform LBP (P=8,R=1) — PURE BOOLEAN form. (unchanged)
// ---------------------------------------------------------------------------
__global__ void lbp_kernel(const float* __restrict__ mo,
                           const float* __restrict__ lb,
                           unsigned long long* __restrict__ maskbits) {
    int m = blockIdx.y;                    // image 0..15: even=pred, odd=mask
    int pix = blockIdx.x * blockDim.x + threadIdx.x;   // 0..262143
    int r = pix >> 9, c = pix & 511;
    int sample = m >> 1;
    const float* img = (m & 1) ? (lb + sample * NPIX) : (mo + sample * NPIX);
    float thr = (m & 1) ? 0.5f : 0.0f;     // sigmoid(x)>0.5 <=> x>0

    int rm = r - (r > 0), rp = r + (r < HH - 1);
    int cm = c - (c > 0), cp = c + (c < WW - 1);
    const float* rowm = img + rm * WW;
    const float* row0 = img + r  * WW;
    const float* rowp = img + rp * WW;

    bool bmm = rowm[cm] > thr, bm0 = rowm[c] > thr, bmp = rowm[cp] > thr;
    bool b0m = row0[cm] > thr, b00 = row0[c] > thr, b0p = row0[cp] > thr;
    bool bpm = rowp[cm] > thr, bp0 = rowp[c] > thr, bpp = rowp[cp] > thr;

    bool r0e = (r == 0), c0e = (c == 0);
    bool t2m = r0e ? bpm : b0m;    // B(row2, cm)
    bool t2c = r0e ? bp0 : b00;    // B(row2, c)
    bool t2p = r0e ? bpp : b0p;    // B(row2, cp)
    bool mc2 = c0e ? bmp : bm0;    // B(rm,  col2)
    bool tc2 = c0e ? t2p : t2c;    // B(row2,col2)
    bool zc2 = c0e ? b0p : b00;    // B(r,   col2)
    bool pc2 = c0e ? bpp : bp0;    // B(rp,  col2)

    unsigned bb =
        (b0p                     ?   1u : 0u)
      | ((bm0 & bmp & t2c & t2p) ?   2u : 0u)
      | (bm0                     ?   4u : 0u)
      | ((bmm & mc2 & t2m & tc2) ?   8u : 0u)
      | (b0m                     ?  16u : 0u)
      | ((b0m & zc2 & bpm & pc2) ?  32u : 0u)
      | (bp0                     ?  64u : 0u)
      | ((b0p & bp0 & bpp)       ? 128u : 0u);

    unsigned rol = ((bb << 1) | (bb >> 7)) & 0xFFu;
    int changes = __popc(bb ^ rol);
    int s = __popc(bb);
    bool maskbit = b00 && (changes <= 2) && (s < 5);   // lbp < THR(=5)

    unsigned long long w = __ballot(maskbit);
    if ((threadIdx.x & 63) == 0)
        maskbits[m * NWORDS + (pix >> 6)] = w;
}

// ---------------------------------------------------------------------------
// Kernel 2: stable row-major compaction to K=1024 packed points per image
// (unchanged)
// ---------------------------------------------------------------------------
__global__ void select_kernel(const unsigned long long* __restrict__ maskbits,
                              unsigned* __restrict__ ptsG) {
    __shared__ unsigned swv[4];
    int m = blockIdx.x, tid = threadIdx.x;
    int lane = tid & 63, wid = tid >> 6;

    for (int i = tid; i < KPTS; i += 256) ptsG[m * KPTS + i] = 0u;
    __syncthreads();

    unsigned running = 0;
    for (int ch = 0; ch < 16; ch++) {
        int w = ch * 256 + tid;
        unsigned long long word = maskbits[m * NWORDS + w];
        unsigned cnt = (unsigned)__popcll(word);

        unsigned x = cnt;                    // intra-wave inclusive scan
#pragma unroll
        for (int d = 1; d < 64; d <<= 1) {
            unsigned y = (unsigned)__shfl_up((int)x, d, 64);
            x += (lane >= d) ? y : 0u;
        }
        if (lane == 63) swv[wid] = x;
        __syncthreads();
        unsigned woff = 0, total = 0;
#pragma unroll
        for (int ww = 0; ww < 4; ww++) {
            unsigned t = swv[ww];
            total += t;
            woff += (ww < wid) ? t : 0u;
        }
        unsigned rank = running + woff + x - cnt;   // exclusive prefix
        while (word) {
            int b = __builtin_ctzll(word);
            word &= word - 1;
            if (rank < (unsigned)KPTS) {
                unsigned p = (unsigned)(w * 64 + b);
                unsigned rr = p >> 9, cc = p & 511u;
                ptsG[m * KPTS + rank] = (rr << 16) | cc;
            }
            rank++;
        }
        running += total;
        if (running >= (unsigned)KPTS) break;   // uniform -> safe
        __syncthreads();   // protect swv before next chunk
    }
}

// ---------------------------------------------------------------------------
// Kernel 3: 2-wave Prim, TWO EXTRACTIONS PER EXCHANGE ROUND.
// Exchange carries per-wave TOP-2 (m,m2) of its 512 owned keys (packed u64,
// one b128 read total). Per round:
//   j1 = min of m's (its key value = global min of old keys);
//   k2cand = global 2nd-min of old keys (from the 4 exchanged values,
//            excluding the gm instance — 2nd-min is either gm-wave's m2 or
//            the other wave's m, both present);
//   gdk = min over LIVE v of dkey(v,j1), computed LOCALLY in every wave
//         from the replicated points + a replicated 16-bit liveness mask
//         (dead nodes would otherwise pollute: their fresh distances to j1
//         are small). j1's own dk is negative -> huge unsigned -> excluded.
//   j2 = min(k2cand, gdk)   [exact: min distributes over elementwise min;
//                            idx-embedded keys make all values distinct]
//   update own keys with BOTH pj1,pj2 (signed-min: dead stays dead,
//   extracted slots self-kill), per-wave top-2 pair-reduce via DPP
//   (boundary lanes get old=0x7FFFFFFF so self-combine can't corrupt m2),
//   single b64 write + ONE barrier per round (was one per extraction).
// Tail: rounds 0..510 produce edges 0..1021; round 511 extracts edge 1022
// only. Extraction order provably identical to sequential Prim; recover/
// final unchanged.
// ---------------------------------------------------------------------------
typedef short v2s __attribute__((ext_vector_type(2)));
typedef unsigned u32x4 __attribute__((ext_vector_type(4)));

#define BIGK 0x7FFFFFFFu

__device__ __forceinline__ int dist2_packed(unsigned a, unsigned b) {
#if __has_builtin(__builtin_amdgcn_sdot2)
    v2s d = __builtin_bit_cast(v2s, a) - __builtin_bit_cast(v2s, b);
    return __builtin_amdgcn_sdot2(d, d, 0, false);
#else
    int dr = (int)(a >> 16) - (int)(b >> 16);
    int dc = (int)(a & 0xFFFFu) - (int)(b & 0xFFFFu);
    return __mul24(dr, dr) + __mul24(dc, dc);
#endif
}

__device__ __forceinline__ unsigned umin3(unsigned a, unsigned b, unsigned c) {
    unsigned t = a < b ? a : b;          // fuses to v_min3_u32
    return t < c ? t : c;
}

template <int CTRL>
__device__ __forceinline__ unsigned umin_dpp(unsigned x) {
    unsigned o = (unsigned)__builtin_amdgcn_update_dpp((int)x, (int)x, CTRL,
                                                       0xf, 0xf, false);
    return o < x ? o : x;
}

// full-wave unsigned-min; result valid in lane 63 only.
__device__ __forceinline__ unsigned wave_min_to_lane63(unsigned x) {
    x = umin_dpp<0x111>(x);   // row_shr:1
    x = umin_dpp<0x112>(x);   // row_shr:2
    x = umin_dpp<0x114>(x);   // row_shr:4
    x = umin_dpp<0x118>(x);   // row_shr:8
    x = umin_dpp<0x142>(x);   // row_bcast:15
    x = umin_dpp<0x143>(x);   // row_bcast:31 -> lane63
    return x;
}

// top-2 pair combine step: windows are disjoint at every level (shr1/2/4/8,
// bcast15, bcast31); lanes receiving no data get old=BIGK so the pair
// combines with (BIGK,BIGK) -> unchanged (self-combine would wrongly set
// m2 = m).
template <int CTRL>
__device__ __forceinline__ void top2_dpp_step(unsigned& a, unsigned& b) {
    unsigned oa = (unsigned)__builtin_amdgcn_update_dpp((int)BIGK, (int)a,
                                                        CTRL, 0xf, 0xf, false);
    unsigned ob = (unsigned)__builtin_amdgcn_update_dpp((int)BIGK, (int)b,
                                                        CTRL, 0xf, 0xf, false);
    unsigned mx = a > oa ? a : oa;
    a = a < oa ? a : oa;
    b = umin3(mx, b, ob);
}

__device__ __forceinline__ void wave_top2_to_lane63(unsigned& a, unsigned& b) {
    top2_dpp_step<0x111>(a, b);
    top2_dpp_step<0x112>(a, b);
    top2_dpp_step<0x114>(a, b);
    top2_dpp_step<0x118>(a, b);
    top2_dpp_step<0x142>(a, b);
    top2_dpp_step<0x143>(a, b);
}

// biased key: coords pre-shifted <<5 so sdot2 gives d2<<10; acc = idx-1024
__device__ __forceinline__ unsigned mk_key(unsigned ps, unsigned qs, int izb) {
#if __has_builtin(__builtin_amdgcn_sdot2)
    v2s d = __builtin_bit_cast(v2s, ps) - __builtin_bit_cast(v2s, qs);
    return (unsigned)__builtin_amdgcn_sdot2(d, d, izb, false);
#else
    int dr = (int)(short)(ps >> 16) - (int)(short)(qs >> 16);
    int dc = (int)(short)(ps & 0xFFFFu) - (int)(short)(qs & 0xFFFFu);
    return (unsigned)(dr * dr + dc * dc + izb);
#endif
}

// uniform select of points[wslot][.] from 16 replicated regs
#define SEL16B(P, B0, B1, B2, B3, res)                                    \
    { unsigned _a0 = B0 ? P##1  : P##0;                                   \
      unsigned _a1 = B0 ? P##3  : P##2;                                   \
      unsigned _a2 = B0 ? P##5  : P##4;                                   \
      unsigned _a3 = B0 ? P##7  : P##6;                                   \
      unsigned _a4 = B0 ? P##9  : P##8;                                   \
      unsigned _a5 = B0 ? P##11 : P##10;                                  \
      unsigned _a6 = B0 ? P##13 : P##12;                                  \
      unsigned _a7 = B0 ? P##15 : P##14;                                  \
      unsigned _c0 = B1 ? _a1 : _a0;                                      \
      unsigned _c1 = B1 ? _a3 : _a2;                                      \
      unsigned _c2 = B1 ? _a5 : _a4;                                      \
      unsigned _c3 = B1 ? _a7 : _a6;                                      \
      unsigned _e0 = B2 ? _c1 : _c0;                                      \
      unsigned _e1 = B2 ? _c3 : _c2;                                      \
      res = B3 ? _e1 : _e0; }

#define LOADP(P, B)                                                       \
    unsigned P##0  = B[( 0 << 6) | lane] << 5;                            \
    unsigned P##1  = B[( 1 << 6) | lane] << 5;                            \
    unsigned P##2  = B[( 2 << 6) | lane] << 5;                            \
    unsigned P##3  = B[( 3 << 6) | lane] << 5;                            \
    unsigned P##4  = B[( 4 << 6) | lane] << 5;                            \
    unsigned P##5  = B[( 5 << 6) | lane] << 5;                            \
    unsigned P##6  = B[( 6 << 6) | lane] << 5;                            \
    unsigned P##7  = B[( 7 << 6) | lane] << 5;                            \
    unsigned P##8  = B[( 8 << 6) | lane] << 5;                            \
    unsigned P##9  = B[( 9 << 6) | lane] << 5;                            \
    unsigned P##10 = B[(10 << 6) | lane] << 5;                            \
    unsigned P##11 = B[(11 << 6) | lane] << 5;                            \
    unsigned P##12 = B[(12 << 6) | lane] << 5;                            \
    unsigned P##13 = B[(13 << 6) | lane] << 5;                            \
    unsigned P##14 = B[(14 << 6) | lane] << 5;                            \
    unsigned P##15 = B[(15 << 6) | lane] << 5;

// masked dkey(v, j1) for replicated slot s (lm bit s must be live)
#define DKM(s)                                                            \
    unsigned md##s;                                                       \
    { unsigned _d = mk_key(p##s, pj1, ii##s);                             \
      md##s = (lm & (1u << s)) ? _d : BIGK; }

#define INLANE_MIN16D(res)                                                \
    { unsigned _m0 = umin3(md0, md1, md2);                                \
      unsigned _m1 = umin3(md3, md4, md5);                                \
      unsigned _m2 = umin3(md6, md7, md8);                                \
      unsigned _m3 = umin3(md9, md10, md11);                              \
      unsigned _m4 = umin3(md12, md13, md14);                             \
      unsigned _ra = umin3(_m0, _m1, _m2);                                \
      unsigned _rb = umin3(_m3, _m4, md15);                               \
      res = _ra < _rb ? _ra : _rb; }

// own-slot signed-min update (dead stays dead; extracted self-kills)
#define OSU(s, PJ)                                                        \
    { unsigned _nk = mk_key(oq##s, PJ, oi##s);                            \
      ok##s = (unsigned)min((int)ok##s, (int)_nk); }

// in-lane top-2 over own 8 slots
#define INLANE_TOP2_8(A, B)                                               \
    { unsigned _a0 = ok0 < ok1 ? ok0 : ok1, _b0 = ok0 < ok1 ? ok1 : ok0;  \
      unsigned _a1 = ok2 < ok3 ? ok2 : ok3, _b1 = ok2 < ok3 ? ok3 : ok2;  \
      unsigned _a2 = ok4 < ok5 ? ok4 : ok5, _b2 = ok4 < ok5 ? ok5 : ok4;  \
      unsigned _a3 = ok6 < ok7 ? ok6 : ok7, _b3 = ok6 < ok7 ? ok7 : ok6;  \
      unsigned _aa = _a0 < _a1 ? _a0 : _a1;                               \
      unsigned _ba = umin3(_a0 > _a1 ? _a0 : _a1, _b0, _b1);              \
      unsigned _ab = _a2 < _a3 ? _a2 : _a3;                               \
      unsigned _bb = umin3(_a2 > _a3 ? _a2 : _a3, _b2, _b3);              \
      A = _aa < _ab ? _aa : _ab;                                          \
      B = umin3(_aa > _ab ? _aa : _ab, _ba, _bb); }

__global__ __launch_bounds__(128, 1) void mst_kernel(const unsigned* __restrict__ ptsG,
                                                     unsigned* __restrict__ edgesG) {
    __shared__ __align__(16) unsigned long long xm64[2][2];  // [par][wave]=(m2<<32)|m
    int tid = threadIdx.x;
    int lane = tid & 63, wid = tid >> 6;         // 2 waves
    int m = blockIdx.x;
    const unsigned* base = ptsG + m * KPTS;
    unsigned pt0s = base[0] << 5;                // uniform self point 0

    LOADP(p, base)                               // replicated point set

    // replicated biased indices ii_s = ((s<<6)|lane) - 1024
    int ii0  = (( 0 << 6) | lane) - 1024;  int ii1  = (( 1 << 6) | lane) - 1024;
    int ii2  = (( 2 << 6) | lane) - 1024;  int ii3  = (( 3 << 6) | lane) - 1024;
    int ii4  = (( 4 << 6) | lane) - 1024;  int ii5  = (( 5 << 6) | lane) - 1024;
    int ii6  = (( 6 << 6) | lane) - 1024;  int ii7  = (( 7 << 6) | lane) - 1024;
    int ii8  = (( 8 << 6) | lane) - 1024;  int ii9  = (( 9 << 6) | lane) - 1024;
    int ii10 = ((10 << 6) | lane) - 1024;  int ii11 = ((11 << 6) | lane) - 1024;
    int ii12 = ((12 << 6) | lane) - 1024;  int ii13 = ((13 << 6) | lane) - 1024;
    int ii14 = ((14 << 6) | lane) - 1024;  int ii15 = ((15 << 6) | lane) - 1024;

    // own key slots: 8 per wave, global slot = wid*8 + s
    int osl = wid << 3;
    int oi0 = (((osl + 0) << 6) | lane) - 1024;
    int oi1 = (((osl + 1) << 6) | lane) - 1024;
    int oi2 = (((osl + 2) << 6) | lane) - 1024;
    int oi3 = (((osl + 3) << 6) | lane) - 1024;
    int oi4 = (((osl + 4) << 6) | lane) - 1024;
    int oi5 = (((osl + 5) << 6) | lane) - 1024;
    int oi6 = (((osl + 6) << 6) | lane) - 1024;
    int oi7 = (((osl + 7) << 6) | lane) - 1024;
    unsigned oq0 = base[((osl + 0) << 6) | lane] << 5;
    unsigned oq1 = base[((osl + 1) << 6) | lane] << 5;
    unsigned oq2 = base[((osl + 2) << 6) | lane] << 5;
    unsigned oq3 = base[((osl + 3) << 6) | lane] << 5;
    unsigned oq4 = base[((osl + 4) << 6) | lane] << 5;
    unsigned oq5 = base[((osl + 5) << 6) | lane] << 5;
    unsigned oq6 = base[((osl + 6) << 6) | lane] << 5;
    unsigned oq7 = base[((osl + 7) << 6) | lane] << 5;
    unsigned ok0 = mk_key(oq0, pt0s, oi0);       // node0 self-kills
    unsigned ok1 = mk_key(oq1, pt0s, oi1);
    unsigned ok2 = mk_key(oq2, pt0s, oi2);
    unsigned ok3 = mk_key(oq3, pt0s, oi3);
    unsigned ok4 = mk_key(oq4, pt0s, oi4);
    unsigned ok5 = mk_key(oq5, pt0s, oi5);
    unsigned ok6 = mk_key(oq6, pt0s, oi6);
    unsigned ok7 = mk_key(oq7, pt0s, oi7);

    unsigned lm = (lane == 0) ? 0xFFFEu : 0xFFFFu;   // node 0 dead
    unsigned* eout = edgesG + m * KPTS;
    unsigned acc = 0;
    int par = 0;

    // prologue: initial per-wave top-2 -> write xm[0]
    {
        unsigned a, b;
        INLANE_TOP2_8(a, b);
        wave_top2_to_lane63(a, b);
        if (lane == 63)
            xm64[0][wid] = ((unsigned long long)b << 32) | a;
    }
    __syncthreads();

#pragma unroll 1
    for (int chk = 0; chk < 16; chk++) {
#pragma unroll 1
        for (int tr = 0; tr < 32; tr++) {
            int r = (chk << 5) + tr;             // round 0..511
            u32x4 A = *reinterpret_cast<const u32x4*>(&xm64[par][0]);
            // A = {m0, m2_0, m1, m2_1}
            unsigned gm = A.x < A.z ? A.x : A.z;

            if (r == 511) {                      // tail: edge 1022 only
                unsigned wk = gm + 1024u;
                acc = (lane == 62) ? wk : acc;
                break;                           // uniform
            }

            unsigned vm1 = gm;
            unsigned wk1 = gm + 1024u;
            acc = (lane == 2 * tr) ? wk1 : acc;

            // global 2nd-min of old keys (exclude the gm instance)
            unsigned mA = (A.x == gm) ? BIGK : A.x;
            unsigned mZ = (A.z == gm) ? BIGK : A.z;
            unsigned k2 = umin3(mA, mZ, A.y < A.w ? A.y : A.w);

            // pj1: SEL16 (bools from VGPR vm1 bits) + readlane
            int wl1 = __builtin_amdgcn_readfirstlane((int)vm1) & 63;
            unsigned sel1;
            {
                bool b0 = (vm1 & 64u)  != 0u;
                bool b1 = (vm1 & 128u) != 0u;
                bool b2 = (vm1 & 256u) != 0u;
                bool b3 = (vm1 & 512u) != 0u;
                SEL16B(p, b0, b1, b2, b3, sel1);
            }
            unsigned pj1 = (unsigned)__builtin_amdgcn_readlane((int)sel1, wl1);

            // liveness: clear j1 (before dk mask)
            {
                unsigned bit = 1u << ((vm1 >> 6) & 15u);
                lm = ((unsigned)lane == (vm1 & 63u)) ? (lm & ~bit) : lm;
            }

            // dk vector (masked) + global reduce -> gdk
            DKM(0)  DKM(1)  DKM(2)  DKM(3)
            DKM(4)  DKM(5)  DKM(6)  DKM(7)
            DKM(8)  DKM(9)  DKM(10) DKM(11)
            DKM(12) DKM(13) DKM(14) DKM(15)
            unsigned g;
            INLANE_MIN16D(g);
            g = wave_min_to_lane63(g);
            unsigned gdk = (unsigned)__builtin_amdgcn_readlane((int)g, 63);

            // second extraction
            unsigned vm2 = k2 < gdk ? k2 : gdk;
            unsigned wk2 = vm2 + 1024u;
            acc = (lane == 2 * tr + 1) ? wk2 : acc;

            int wl2 = __builtin_amdgcn_readfirstlane((int)vm2) & 63;
            unsigned sel2;
            {
                bool b0 = (vm2 & 64u)  != 0u;
                bool b1 = (vm2 & 128u) != 0u;
                bool b2 = (vm2 & 256u) != 0u;
                bool b3 = (vm2 & 512u) != 0u;
                SEL16B(p, b0, b1, b2, b3, sel2);
            }
            unsigned pj2 = (unsigned)__builtin_amdgcn_readlane((int)sel2, wl2);

            {
                unsigned bit = 1u << ((vm2 >> 6) & 15u);
                lm = ((unsigned)lane == (vm2 & 63u)) ? (lm & ~bit) : lm;
            }

            // own-key updates with both extracted nodes
            OSU(0, pj1) OSU(1, pj1) OSU(2, pj1) OSU(3, pj1)
            OSU(4, pj1) OSU(5, pj1) OSU(6, pj1) OSU(7, pj1)
            OSU(0, pj2) OSU(1, pj2) OSU(2, pj2) OSU(3, pj2)
            OSU(4, pj2) OSU(5, pj2) OSU(6, pj2) OSU(7, pj2)

            // per-wave top-2 + single b64 write + ONE barrier per round
            unsigned a, b;
            INLANE_TOP2_8(a, b);
            wave_top2_to_lane63(a, b);
            if (lane == 63)
                xm64[par ^ 1][wid] = ((unsigned long long)b << 32) | a;
            __syncthreads();
            par ^= 1;
        }
        // acc identical in both waves; alternate the chunk stores
        if (wid == (chk & 1)) eout[(chk << 6) + lane] = acc;
    }
}

// ---------------------------------------------------------------------------
// Kernel 4 (phase 2): recover src per edge + per-edge (Dp-Dm)^2. (unchanged)
// ---------------------------------------------------------------------------
__global__ void recover_kernel(const unsigned* __restrict__ ptsG,
                               const unsigned* __restrict__ edgesG,
                               float* __restrict__ contrib) {
    __shared__ unsigned sS[KPTS];
    __shared__ unsigned sO[KPTS];
    __shared__ unsigned short sT[KPTS];   // extraction time + 1 (0 = root)
    int g = blockIdx.x, m = blockIdx.y;
    int tid = threadIdx.x;
    int partner = m ^ 1;

    for (int i = tid; i < KPTS; i += 256) {
        sS[i] = ptsG[m * KPTS + i];
        sO[i] = ptsG[partner * KPTS + i];
    }
    for (int e = tid; e < KPTS - 1; e += 256) {
        unsigned wkk = edgesG[m * KPTS + e];
        sT[wkk & 1023u] = (unsigned short)(e + 1);
    }
    if (tid == 0) sT[0] = 0;
    __syncthreads();

    int lane = tid & 63, w = tid >> 6;
    for (int k = 0; k < 16; k++) {
        int e = g * 64 + w * 16 + k;
        if (e >= KPTS - 1) break;            // only e=1023 (g=15,w=3,k=15)
        unsigned wk = edgesG[m * KPTS + e];
        unsigned j = wk & 1023u;
        unsigned d2p = wk >> 10;
        unsigned pj = sS[j];
        unsigned te1 = (unsigned)(e + 1);

        unsigned best = 0xFFFFFFFFu;
#pragma unroll
        for (int i = 0; i < 16; i++) {
            int v = i * 64 + lane;
            unsigned pv = sS[v];
            int d2 = dist2_packed(pv, pj);
            unsigned tv1 = (unsigned)sT[v];
            bool qual = ((unsigned)d2 == d2p) && (tv1 < te1);
            unsigned cand = qual ? ((tv1 << 10) | (unsigned)v) : 0xFFFFFFFFu;
            best = cand < best ? cand : best;
        }
#pragma unroll
        for (int dd = 32; dd; dd >>= 1) {
            unsigned o = (unsigned)__shfl_xor((int)best, dd, 64);
            best = o < best ? o : best;
        }
        unsigned vsrc = best & 1023u;
        if (lane == 0) {
            unsigned oj = sO[j], os = sO[vsrc];
            float Dp = __fsqrt_rn((float)d2p);
            float Dm = __fsqrt_rn((float)dist2_packed(oj, os));
            float diff = Dp - Dm;
            contrib[m * (KPTS - 1) + e] = diff * diff;
        }
    }
}

// ---------------------------------------------------------------------------
// Kernel 5: per-image f64 sum (extraction order, deterministic) -> loss
// (unchanged)
// ---------------------------------------------------------------------------
__global__ void final_kernel(const float* __restrict__ contrib,
                             float* __restrict__ out) {
    __shared__ double part[NIMG];
    int t = threadIdx.x;
    if (t < NIMG) {
        double s = 0.0;
        for (int e = 0; e < KPTS - 1; e++)
            s += (double)contrib[t * (KPTS - 1) + e];
        part[t] = sqrt(s);
    }
    __syncthreads();
    if (t == 0) {
        double tot = 0.0;
        for (int i = 0; i < NIMG; i++) tot += part[i];
        out[0] = (float)(0.1 * tot / 8.0);
    }
}

// ---------------------------------------------------------------------------
// ws layout:
//   [0,512K)     maskbits (lbp->select), then DEAD:
//   [0,64K)      edgesG   (mst->recover)   — overlaps dead maskbits
//   [64K,128K)   contrib  (recover->final) — overlaps dead maskbits
//   [512K,576K)  ptsG     (select->mst/recover)
// ---------------------------------------------------------------------------
extern "C" void kernel_launch(void* const* d_in, const int* in_sizes, int n_in,
                              void* d_out, int out_size, void* d_ws, size_t ws_size,
                              hipStream_t stream) {
    const float* mo = (const float*)d_in[1];   // model_output
    const float* lb = (const float*)d_in[2];   // labels

    unsigned long long* maskbits = (unsigned long long*)d_ws;
    unsigned* edgesG = (unsigned*)d_ws;
    float* contrib = (float*)((char*)d_ws + (size_t)64 * 1024);
    unsigned* ptsG = (unsigned*)((char*)d_ws + (size_t)NIMG * NWORDS * 8);
    float* out = (float*)d_out;

    lbp_kernel<<<dim3(NPIX / 256, NIMG), 256, 0, stream>>>(mo, lb, maskbits);
    select_kernel<<<NIMG, 256, 0, stream>>>(maskbits, ptsG);
    mst_kernel<<<NIMG, 128, 0, stream>>>(ptsG, edgesG);
    recover_kernel<<<dim3(16, NIMG), 256, 0, stream>>>(ptsG, edgesG, contrib);
    final_kernel<<<1, 64, 0, stream>>>(contrib, out);
}